// Round 1
// 329.031 us; speedup vs baseline: 1.1738x; 1.1738x over previous
//
#include <hip/hip_runtime.h>
#include <hip/hip_bf16.h>
#include <hip/hip_fp16.h>
#include <math.h>

// QAT GPT2 MLP + LoRA on MI355X — fp32 in/out.
// Round 6: replace quant_h_t2 (99us, 20% VALU, 0% MFMA, latency/reduction
// bound) with a fused streaming kernel: each wave owns 16 rows x 512 cols of
// h(fp16); the same 16B h-load feeds mfma_f32_16x16x32_f16 (t2 = h.A^T, HW
// k-reduction, no shuffles) AND the i8 quantizer. A_proj pre-converted to
// fp16 [16][4096] (rows 8-15 zero). i8 stored in-place in CHUNKED layout
// off(col) = (col>>9)*1024 + (col&511) so each wave writes only bytes it
// alone read (race-free under K-split). gemm2 walks the chunked layout via
// +640-every-4th-iteration address increment. t2 accumulated by atomicAdd
// into a zeroed buffer. Everything else (int8 MFMA GEMMs, XOR-swizzled LDS,
// erf GELU) unchanged from round 5 (386us).

typedef unsigned short u16;
typedef unsigned int u32;
typedef signed char i8;
typedef int i32x4 __attribute__((ext_vector_type(4)));
typedef _Float16 f16;
typedef f16 f16x8 __attribute__((ext_vector_type(8)));
typedef float f32x4 __attribute__((ext_vector_type(4)));

#define ASYNC16(gp, lp)                                                        \
  __builtin_amdgcn_global_load_lds(                                            \
      (__attribute__((address_space(1))) void*)(gp),                           \
      (__attribute__((address_space(3))) void*)(lp), 16, 0, 0)

// quantize to int: q = clip(rint(v/s), -128, 127)
__device__ __forceinline__ int quanti(float v, float inv) {
  float q = rintf(v * inv);
  q = fminf(fmaxf(q, -128.0f), 127.0f);
  return (int)q;
}

__device__ __forceinline__ float load_scale(const u32* slot) {
  return fmaxf(__uint_as_float(*slot) * (1.0f / 127.0f), 1e-8f);
}

// exact-erf GELU via Abramowitz-Stegun 7.1.26 (|erf err| <= 1.5e-7)
__device__ __forceinline__ float gelu_erf(float v) {
  float z = fabsf(v) * 0.70710678118654752f;
  float t = __builtin_amdgcn_rcpf(fmaf(0.3275911f, z, 1.0f));
  float poly =
      t * fmaf(t,
               fmaf(t,
                    fmaf(t, fmaf(t, 1.061405429f, -1.453152027f),
                         1.421413741f),
                    -0.284496736f),
               0.254829592f);
  float e = fmaf(-poly, exp2f(-z * z * 1.4426950408889634f), 1.0f);
  return 0.5f * v * fmaf(copysignf(e, v), 1.0f, 1.0f);
}

// -------------------- absmax over fp32 tensor (float4 grid-stride) ----------
__global__ void absmax_kernel(const float* __restrict__ x, int n4,
                              u32* __restrict__ slot) {
  float m = 0.0f;
  int stride = gridDim.x * blockDim.x;
  for (int i = blockIdx.x * blockDim.x + threadIdx.x; i < n4; i += stride) {
    float4 v = ((const float4*)x)[i];
    m = fmaxf(m, fmaxf(fmaxf(fabsf(v.x), fabsf(v.y)),
                       fmaxf(fabsf(v.z), fabsf(v.w))));
  }
#pragma unroll
  for (int off = 32; off > 0; off >>= 1) m = fmaxf(m, __shfl_down(m, off));
  __shared__ float wmax[4];
  int lane = threadIdx.x & 63, wave = threadIdx.x >> 6;
  if (lane == 0) wmax[wave] = m;
  __syncthreads();
  if (threadIdx.x == 0) {
    m = fmaxf(fmaxf(wmax[0], wmax[1]), fmaxf(wmax[2], wmax[3]));
    atomicMax(slot, __float_as_uint(m));  // positive floats: bit-monotone
  }
}

// ---------------- quantize W (fp32 in, packed i8 out) -----------------------
// each thread handles 16 floats -> one uint4 (16 i8) store
__global__ void quant_w_kernel(const float* __restrict__ w, int n16,
                               const u32* __restrict__ slot,
                               i8* __restrict__ q) {
  float inv = 1.0f / load_scale(slot);
  int stride = gridDim.x * blockDim.x;
  for (int i = blockIdx.x * blockDim.x + threadIdx.x; i < n16; i += stride) {
    const float4* src = (const float4*)w + i * 4;
    u32 pk[4];
#pragma unroll
    for (int c = 0; c < 4; c++) {
      float4 v = src[c];
      pk[c] = ((u32)(quanti(v.x, inv) & 255)) |
              ((u32)(quanti(v.y, inv) & 255) << 8) |
              ((u32)(quanti(v.z, inv) & 255) << 16) |
              ((u32)(quanti(v.w, inv) & 255) << 24);
    }
    uint4 o = {pk[0], pk[1], pk[2], pk[3]};
    ((uint4*)q)[i] = o;
  }
}

// ---- quantize x + t1[m][r] = sum_i x[m,i]*Afc[r,i]  (block per row) --------
__global__ void quant_x_t1_kernel(const float* __restrict__ x,
                                  const float* __restrict__ A,  // [8][1024]
                                  const u32* __restrict__ slot,
                                  i8* __restrict__ q,
                                  float* __restrict__ t1) {
  int row = blockIdx.x, tid = threadIdx.x;
  float inv = 1.0f / load_scale(slot);
  float4 v = ((const float4*)(x + (long)row * 1024))[tid];
  u32 pk = ((u32)(quanti(v.x, inv) & 255)) |
           ((u32)(quanti(v.y, inv) & 255) << 8) |
           ((u32)(quanti(v.z, inv) & 255) << 16) |
           ((u32)(quanti(v.w, inv) & 255) << 24);
  ((u32*)(q + (long)row * 1024))[tid] = pk;
  float p[8];
#pragma unroll
  for (int r = 0; r < 8; r++) {
    float4 a = ((const float4*)(A + r * 1024))[tid];
    p[r] = v.x * a.x + v.y * a.y + v.z * a.z + v.w * a.w;
  }
#pragma unroll
  for (int r = 0; r < 8; r++)
#pragma unroll
    for (int off = 32; off > 0; off >>= 1) p[r] += __shfl_down(p[r], off);
  __shared__ float red[4][8];
  int lane = tid & 63, wave = tid >> 6;
  if (lane == 0) {
#pragma unroll
    for (int r = 0; r < 8; r++) red[wave][r] = p[r];
  }
  __syncthreads();
  if (tid < 8)
    t1[(long)row * 8 + tid] =
        red[0][tid] + red[1][tid] + red[2][tid] + red[3][tid];
}

// ---- convert A_proj [8][4096] fp32 -> [16][4096] fp16, rows 8-15 zero ------
__global__ void conv_a16_kernel(const float* __restrict__ A,
                                f16* __restrict__ Ah) {
  int i = blockIdx.x * blockDim.x + threadIdx.x;  // 8192 threads x 8 vals
  int base = i * 8;
  if (base < 8 * 4096) {
    float4 v0 = ((const float4*)(A + base))[0];
    float4 v1 = ((const float4*)(A + base))[1];
    f16x8 o = {(f16)v0.x, (f16)v0.y, (f16)v0.z, (f16)v0.w,
               (f16)v1.x, (f16)v1.y, (f16)v1.z, (f16)v1.w};
    *(f16x8*)(Ah + base) = o;
  } else {
    f16x8 z = {};
    *(f16x8*)(Ah + base) = z;
  }
}

// ---- fused: quantize h (fp16 -> i8 in place, chunked) + t2 = h.A^T via MFMA
// Wave owns rows [m0, m0+16) x cols [k0, k0+512).  A-frag of
// mfma_f32_16x16x32_f16: lane(quad,l15) holds A[m=l15][k=quad*8..+7] -> one
// 16B load of h feeds both the MFMA and the quantizer.  B-operand is
// Ah[16][4096] fp16 (n=l15 -> LoRA rank index; rows 8-15 zero).
// C/D layout: col=lane&15 (=r), row=quad*4+reg (=m within 16)  [m89].
// i8 stored at row*8192 + (col>>9)*1024 + (col&511): strictly inside the
// fp16 bytes THIS wave read -> no cross-wave in-place race.
__launch_bounds__(256) __global__
    void quant_h_t2_fused(u16* __restrict__ h,        // [8192][4096] fp16
                          const f16* __restrict__ Ah, // [16][4096]
                          const u32* __restrict__ slot,
                          float* __restrict__ t2) {   // [8192][8], pre-zeroed
  int tid = threadIdx.x;
  int lane = tid & 63, wave = tid >> 6;
  int quad = lane >> 4, l15 = lane & 15;
  int bx = blockIdx.x;                       // k-chunk index [0,8)
  long m0 = (long)blockIdx.y * 64 + wave * 16;
  long row = m0 + l15;
  int k0 = bx * 512;
  float inv = 1.0f / load_scale(slot);

  const u16* hp = h + row * 4096 + k0 + quad * 8;
  const f16* ap = Ah + l15 * 4096 + k0 + quad * 8;
  f32x4 acc = {0.0f, 0.0f, 0.0f, 0.0f};
  u32 q[32];
#pragma unroll
  for (int s = 0; s < 16; s++) {
    uint4 hv = *(const uint4*)(hp + s * 32);   // 8 fp16 of h
    f16x8 af = *(const f16x8*)&hv;
    f16x8 bf = *(const f16x8*)(ap + s * 32);
    acc = __builtin_amdgcn_mfma_f32_16x16x32_f16(af, bf, acc, 0, 0, 0);
    u32 uu[4] = {hv.x, hv.y, hv.z, hv.w};
#pragma unroll
    for (int c = 0; c < 2; c++) {
      float2 f0 = __half22float2(*(__half2*)&uu[2 * c]);
      float2 f1 = __half22float2(*(__half2*)&uu[2 * c + 1]);
      q[2 * s + c] = ((u32)(quanti(f0.x, inv) & 255)) |
                     ((u32)(quanti(f0.y, inv) & 255) << 8) |
                     ((u32)(quanti(f1.x, inv) & 255) << 16) |
                     ((u32)(quanti(f1.y, inv) & 255) << 24);
    }
  }
  // all fp16 reads of this wave's region are consumed; pin order, then
  // overwrite with packed i8 (chunked layout, subset of read bytes).
  asm volatile("" ::: "memory");
  i8* op = (i8*)h + row * 8192 + bx * 1024 + quad * 8;
#pragma unroll
  for (int s = 0; s < 16; s++) {
    uint2 o = {q[2 * s], q[2 * s + 1]};
    *(uint2*)(op + s * 32) = o;
  }
  // t2 partial accumulate (k-split across blockIdx.x -> atomicAdd)
  if (l15 < 8) {
#pragma unroll
    for (int r = 0; r < 4; r++) {
      long m = m0 + quad * 4 + r;
      atomicAdd(&t2[m * 8 + l15], acc[r]);
    }
  }
}

// ------------- main GEMM: C = Aq * Bq^T (i8), 128x128 tile, BK=128 ---------
// A: [M] rows stride lda bytes, B: [N] rows stride ldb bytes, K-major i8.
// LDS XOR-swizzle: phys 16B-chunk p at row r holds logical chunk p^(r&7).
// MFMA: v_mfma_i32_16x16x64_i8, A-frag = 16 i8 at [m=l15][k=quad*16+j].
// MODE 0: *scale + bias + 2*t.Bl, GELU(erf), store FP16 h, absmax(h).
// MODE 1: *scale + bias + 2*t.Bl, store fp32 to d_out.  A is in CHUNKED
//         layout (i8 of col c at byte (c>>9)*1024 + (c&511), rowstride 8192):
//         the 128B K-window advances by 640 instead of 128 every 4th iter.
template <int MODE>
__launch_bounds__(256) __global__
    void gemm_kernel(const i8* __restrict__ A, const i8* __restrict__ B,
                     int N, int K, int lda, int ldb,
                     const float* __restrict__ bias,
                     const float* __restrict__ tl,   // [M][8] f32
                     const float* __restrict__ Bl,   // [N][8] f32
                     const u32* __restrict__ scales, int sa, int sb,
                     void* __restrict__ outp, u32* __restrict__ hmax) {
  __shared__ i8 As[128 * 128];
  __shared__ i8 Bs[128 * 128];
  __shared__ u32 bmax;
  int tid = threadIdx.x;
  int lane = tid & 63, wave = tid >> 6;
  int quad = lane >> 4, l15 = lane & 15;
  int wm = (wave & 1) * 64, wn = (wave >> 1) * 64;
  long m0 = (long)blockIdx.y * 128;
  long n0 = (long)blockIdx.x * 128;
  if (MODE == 0 && tid == 0) bmax = 0u;

  // staging: 1024 chunks of 16B per operand; row = c>>3, swizzled k-chunk
  const i8* gA[4];
  const i8* gB[4];
  int ldsOff[4];
#pragma unroll
  for (int i = 0; i < 4; i++) {
    int c = i * 256 + tid;
    int row = c >> 3;
    int kc = ((c & 7) ^ (row & 7)) * 16;  // swizzled source k-offset (bytes)
    gA[i] = A + (m0 + row) * lda + kc;
    gB[i] = B + (n0 + row) * ldb + kc;
    ldsOff[i] = c * 16;
  }
  // fragment-read swizzled chunk byte offsets: chunk = (kk*4+quad)^(l15&7)
  int s0 = (quad ^ (l15 & 7)) * 16;
  int s1 = s0 ^ 64;

  i32x4 acc[4][4] = {};
  int nit = K >> 7;
  for (int k = 0; k < nit; k++) {
    int adv = (MODE == 1 && (k & 3) == 3) ? 640 : 128;
#pragma unroll
    for (int i = 0; i < 4; i++) {
      ASYNC16(gA[i], As + ldsOff[i]);
      ASYNC16(gB[i], Bs + ldsOff[i]);
      gA[i] += adv;
      gB[i] += 128;
    }
    __syncthreads();
#pragma unroll
    for (int kk = 0; kk < 2; kk++) {
      int ko = kk ? s1 : s0;
      i32x4 af[4], bfr[4];
#pragma unroll
      for (int i = 0; i < 4; i++)
        af[i] = *(const i32x4*)(As + (wm + i * 16 + l15) * 128 + ko);
#pragma unroll
      for (int j = 0; j < 4; j++)
        bfr[j] = *(const i32x4*)(Bs + (wn + j * 16 + l15) * 128 + ko);
#pragma unroll
      for (int i = 0; i < 4; i++)
#pragma unroll
        for (int j = 0; j < 4; j++)
          acc[i][j] = __builtin_amdgcn_mfma_i32_16x16x64_i8(
              af[i], bfr[j], acc[i][j], 0, 0, 0);
    }
    __syncthreads();
  }

  // epilogue
  float scale = load_scale(scales + sa) * load_scale(scales + sb);
  float biasv[4];
  float4 bl0[4], bl1[4];
#pragma unroll
  for (int j = 0; j < 4; j++) {
    long n = n0 + wn + j * 16 + l15;
    biasv[j] = bias[n];
    bl0[j] = ((const float4*)(Bl + n * 8))[0];
    bl1[j] = ((const float4*)(Bl + n * 8))[1];
  }
  float lmax = 0.0f;
#pragma unroll
  for (int i = 0; i < 4; i++) {
#pragma unroll
    for (int r = 0; r < 4; r++) {
      long m = m0 + wm + i * 16 + quad * 4 + r;
      float4 t0 = ((const float4*)(tl + m * 8))[0];
      float4 t1v = ((const float4*)(tl + m * 8))[1];
#pragma unroll
      for (int j = 0; j < 4; j++) {
        long n = n0 + wn + j * 16 + l15;
        float lora = t0.x * bl0[j].x + t0.y * bl0[j].y + t0.z * bl0[j].z +
                     t0.w * bl0[j].w + t1v.x * bl1[j].x + t1v.y * bl1[j].y +
                     t1v.z * bl1[j].z + t1v.w * bl1[j].w;
        float v = (float)acc[i][j][r] * scale + biasv[j] + 2.0f * lora;
        if (MODE == 0) {
          float hv = gelu_erf(v);
          __half hh = __float2half_rn(hv);
          ((u16*)outp)[m * N + n] = *(u16*)&hh;
          lmax = fmaxf(lmax, fabsf(hv));
        } else {
          ((float*)outp)[m * N + n] = v;
        }
      }
    }
  }
  if (MODE == 0) {
    atomicMax(&bmax, __float_as_uint(lmax));
    __syncthreads();
    if (tid == 0) atomicMax(hmax, bmax);
  }
}

extern "C" void kernel_launch(void* const* d_in, const int* in_sizes, int n_in,
                              void* d_out, int out_size, void* d_ws,
                              size_t ws_size, hipStream_t stream) {
  const float* x = (const float*)d_in[0];    // [8192][1024]
  const float* Wfc = (const float*)d_in[1];  // [4096][1024]
  const float* bfc = (const float*)d_in[2];  // [4096]
  const float* Afc = (const float*)d_in[3];  // [8][1024]
  const float* Bfc = (const float*)d_in[4];  // [4096][8]
  const float* Wpr = (const float*)d_in[5];  // [1024][4096]
  const float* bpr = (const float*)d_in[6];  // [1024]
  const float* Apr = (const float*)d_in[7];  // [8][4096]
  const float* Bpr = (const float*)d_in[8];  // [1024][8]
  float* out = (float*)d_out;                // fp32 [8192][1024]

  char* w = (char*)d_ws;
  u32* scales = (u32*)w;                   // 4 slots (fp32 bits): x, Wfc, Wpr, h
  float* t1 = (float*)(w + 256);           // [8192][8]
  float* t2 = (float*)(w + 256 + 262144);  // [8192][8]
  i8* xq = (i8*)(w + 524544);              // [8192][1024] i8
  f16* aprh = (f16*)(w + 8913152);         // [16][4096] fp16 (in xq..wq1 gap)
  i8* wq1 = (i8*)(w + 9437184);            // [4096][1024] i8
  i8* wq2 = (i8*)(w + 13631488);           // [1024][4096] i8
  u16* hq = (u16*)(w + 17825792);          // [8192][4096] fp16 h; i8 in place
  if (ws_size < 84934656) return;          // need ~81 MiB scratch

  hipMemsetAsync(scales, 0, 256, stream);
  hipMemsetAsync(t2, 0, 262144, stream);   // t2 accumulated via atomicAdd
  conv_a16_kernel<<<64, 256, 0, stream>>>(Apr, aprh);
  absmax_kernel<<<1024, 256, 0, stream>>>(x, 8192 * 1024 / 4, scales + 0);
  absmax_kernel<<<512, 256, 0, stream>>>(Wfc, 4096 * 1024 / 4, scales + 1);
  absmax_kernel<<<512, 256, 0, stream>>>(Wpr, 4096 * 1024 / 4, scales + 2);
  quant_x_t1_kernel<<<8192, 256, 0, stream>>>(x, Afc, scales + 0, xq, t1);
  quant_w_kernel<<<256, 256, 0, stream>>>(Wfc, 4096 * 1024 / 16, scales + 1,
                                          wq1);
  quant_w_kernel<<<256, 256, 0, stream>>>(Wpr, 4096 * 1024 / 16, scales + 2,
                                          wq2);
  gemm_kernel<0><<<dim3(32, 64), 256, 0, stream>>>(
      xq, wq1, 4096, 1024, 1024, 1024, bfc, t1, Bfc, scales, 0, 1, hq,
      scales + 3);
  quant_h_t2_fused<<<dim3(8, 128), 256, 0, stream>>>(hq, aprh, scales + 3, t2);
  gemm_kernel<1><<<dim3(8, 64), 256, 0, stream>>>(
      (const i8*)hq, wq2, 1024, 4096, 8192, 4096, bpr, t2, Bpr, scales, 3, 2,
      out, nullptr);
}

// Round 2
// 320.902 us; speedup vs baseline: 1.2035x; 1.0253x over previous
//
#include <hip/hip_runtime.h>
#include <hip/hip_bf16.h>
#include <hip/hip_fp16.h>
#include <math.h>

// QAT GPT2 MLP + LoRA on MI355X — fp32 in/out.
// Round 7: port both int8 GEMMs to the 256-tile 8-phase pipelined schedule
// (guide §5 template, T2+T3+T4+T5): raw s_barrier (no vmcnt(0) drain),
// 4 phases per BK=128 K-tile, each {ds_read frags | stage 1 half-tile ->
// barrier -> lgkmcnt(0) -> setprio(1) -> MFMA cluster -> setprio(0) ->
// barrier}, ONE counted vmcnt(4) per K-tile. Stage-into-consumed-half
// discipline: A-halves of the live buffer are fully read after phase 2,
// B after phase 3; A(t+2) staged at ph3/ph4, B(t+1) staged at ph1/ph2 of
// the NEXT tile's window (prefetch distance = dbuf). XCD-bijective block
// swizzle (nwg%8==0 for both grids). Round-6 fused quant_h_t2 (MFMA t2 +
// in-place chunked i8) kept; round-5 XOR LDS swizzle + erf GELU kept.
// gemm1: BM=256 BN=256, 8 waves 2Mx4N. gemm2: BM=256 BN=128, 4Mx2N
// (grid (8,32)=256 blocks = exactly 1/CU; BN=256 would idle half the GPU).

typedef unsigned short u16;
typedef unsigned int u32;
typedef signed char i8;
typedef int i32x4 __attribute__((ext_vector_type(4)));
typedef _Float16 f16;
typedef f16 f16x8 __attribute__((ext_vector_type(8)));
typedef float f32x4 __attribute__((ext_vector_type(4)));

#define ASYNC16(gp, lp)                                                        \
  __builtin_amdgcn_global_load_lds(                                            \
      (__attribute__((address_space(1))) void*)(gp),                           \
      (__attribute__((address_space(3))) void*)(lp), 16, 0, 0)

#define VMCNT(N) asm volatile("s_waitcnt vmcnt(" #N ")" ::: "memory")
#define LGKM0                                                                  \
  do {                                                                         \
    asm volatile("s_waitcnt lgkmcnt(0)" ::: "memory");                         \
    __builtin_amdgcn_sched_barrier(0);                                         \
  } while (0)
#define SBAR __builtin_amdgcn_s_barrier()

// quantize to int: q = clip(rint(v/s), -128, 127)
__device__ __forceinline__ int quanti(float v, float inv) {
  float q = rintf(v * inv);
  q = fminf(fmaxf(q, -128.0f), 127.0f);
  return (int)q;
}

__device__ __forceinline__ float load_scale(const u32* slot) {
  return fmaxf(__uint_as_float(*slot) * (1.0f / 127.0f), 1e-8f);
}

// exact-erf GELU via Abramowitz-Stegun 7.1.26 (|erf err| <= 1.5e-7)
__device__ __forceinline__ float gelu_erf(float v) {
  float z = fabsf(v) * 0.70710678118654752f;
  float t = __builtin_amdgcn_rcpf(fmaf(0.3275911f, z, 1.0f));
  float poly =
      t * fmaf(t,
               fmaf(t,
                    fmaf(t, fmaf(t, 1.061405429f, -1.453152027f),
                         1.421413741f),
                    -0.284496736f),
               0.254829592f);
  float e = fmaf(-poly, exp2f(-z * z * 1.4426950408889634f), 1.0f);
  return 0.5f * v * fmaf(copysignf(e, v), 1.0f, 1.0f);
}

// -------------------- absmax over fp32 tensor (float4 grid-stride) ----------
__global__ void absmax_kernel(const float* __restrict__ x, int n4,
                              u32* __restrict__ slot) {
  float m = 0.0f;
  int stride = gridDim.x * blockDim.x;
  for (int i = blockIdx.x * blockDim.x + threadIdx.x; i < n4; i += stride) {
    float4 v = ((const float4*)x)[i];
    m = fmaxf(m, fmaxf(fmaxf(fabsf(v.x), fabsf(v.y)),
                       fmaxf(fabsf(v.z), fabsf(v.w))));
  }
#pragma unroll
  for (int off = 32; off > 0; off >>= 1) m = fmaxf(m, __shfl_down(m, off));
  __shared__ float wmax[4];
  int lane = threadIdx.x & 63, wave = threadIdx.x >> 6;
  if (lane == 0) wmax[wave] = m;
  __syncthreads();
  if (threadIdx.x == 0) {
    m = fmaxf(fmaxf(wmax[0], wmax[1]), fmaxf(wmax[2], wmax[3]));
    atomicMax(slot, __float_as_uint(m));  // positive floats: bit-monotone
  }
}

// ---------------- quantize W (fp32 in, packed i8 out) -----------------------
__global__ void quant_w_kernel(const float* __restrict__ w, int n16,
                               const u32* __restrict__ slot,
                               i8* __restrict__ q) {
  float inv = 1.0f / load_scale(slot);
  int stride = gridDim.x * blockDim.x;
  for (int i = blockIdx.x * blockDim.x + threadIdx.x; i < n16; i += stride) {
    const float4* src = (const float4*)w + i * 4;
    u32 pk[4];
#pragma unroll
    for (int c = 0; c < 4; c++) {
      float4 v = src[c];
      pk[c] = ((u32)(quanti(v.x, inv) & 255)) |
              ((u32)(quanti(v.y, inv) & 255) << 8) |
              ((u32)(quanti(v.z, inv) & 255) << 16) |
              ((u32)(quanti(v.w, inv) & 255) << 24);
    }
    uint4 o = {pk[0], pk[1], pk[2], pk[3]};
    ((uint4*)q)[i] = o;
  }
}

// ---- quantize x + t1[m][r] = sum_i x[m,i]*Afc[r,i]  (block per row) --------
__global__ void quant_x_t1_kernel(const float* __restrict__ x,
                                  const float* __restrict__ A,  // [8][1024]
                                  const u32* __restrict__ slot,
                                  i8* __restrict__ q,
                                  float* __restrict__ t1) {
  int row = blockIdx.x, tid = threadIdx.x;
  float inv = 1.0f / load_scale(slot);
  float4 v = ((const float4*)(x + (long)row * 1024))[tid];
  u32 pk = ((u32)(quanti(v.x, inv) & 255)) |
           ((u32)(quanti(v.y, inv) & 255) << 8) |
           ((u32)(quanti(v.z, inv) & 255) << 16) |
           ((u32)(quanti(v.w, inv) & 255) << 24);
  ((u32*)(q + (long)row * 1024))[tid] = pk;
  float p[8];
#pragma unroll
  for (int r = 0; r < 8; r++) {
    float4 a = ((const float4*)(A + r * 1024))[tid];
    p[r] = v.x * a.x + v.y * a.y + v.z * a.z + v.w * a.w;
  }
#pragma unroll
  for (int r = 0; r < 8; r++)
#pragma unroll
    for (int off = 32; off > 0; off >>= 1) p[r] += __shfl_down(p[r], off);
  __shared__ float red[4][8];
  int lane = tid & 63, wave = tid >> 6;
  if (lane == 0) {
#pragma unroll
    for (int r = 0; r < 8; r++) red[wave][r] = p[r];
  }
  __syncthreads();
  if (tid < 8)
    t1[(long)row * 8 + tid] =
        red[0][tid] + red[1][tid] + red[2][tid] + red[3][tid];
}

// ---- convert A_proj [8][4096] fp32 -> [16][4096] fp16, rows 8-15 zero ------
__global__ void conv_a16_kernel(const float* __restrict__ A,
                                f16* __restrict__ Ah) {
  int i = blockIdx.x * blockDim.x + threadIdx.x;  // 8192 threads x 8 vals
  int base = i * 8;
  if (base < 8 * 4096) {
    float4 v0 = ((const float4*)(A + base))[0];
    float4 v1 = ((const float4*)(A + base))[1];
    f16x8 o = {(f16)v0.x, (f16)v0.y, (f16)v0.z, (f16)v0.w,
               (f16)v1.x, (f16)v1.y, (f16)v1.z, (f16)v1.w};
    *(f16x8*)(Ah + base) = o;
  } else {
    f16x8 z = {};
    *(f16x8*)(Ah + base) = z;
  }
}

// ---- fused: quantize h (fp16 -> i8 in place, chunked) + t2 = h.A^T via MFMA
__launch_bounds__(256) __global__
    void quant_h_t2_fused(u16* __restrict__ h,        // [8192][4096] fp16
                          const f16* __restrict__ Ah, // [16][4096]
                          const u32* __restrict__ slot,
                          float* __restrict__ t2) {   // [8192][8], pre-zeroed
  int tid = threadIdx.x;
  int lane = tid & 63, wave = tid >> 6;
  int quad = lane >> 4, l15 = lane & 15;
  int bx = blockIdx.x;                       // k-chunk index [0,8)
  long m0 = (long)blockIdx.y * 64 + wave * 16;
  long row = m0 + l15;
  int k0 = bx * 512;
  float inv = 1.0f / load_scale(slot);

  const u16* hp = h + row * 4096 + k0 + quad * 8;
  const f16* ap = Ah + l15 * 4096 + k0 + quad * 8;
  f32x4 acc = {0.0f, 0.0f, 0.0f, 0.0f};
  u32 q[32];
#pragma unroll
  for (int s = 0; s < 16; s++) {
    uint4 hv = *(const uint4*)(hp + s * 32);   // 8 fp16 of h
    f16x8 af = *(const f16x8*)&hv;
    f16x8 bf = *(const f16x8*)(ap + s * 32);
    acc = __builtin_amdgcn_mfma_f32_16x16x32_f16(af, bf, acc, 0, 0, 0);
    u32 uu[4] = {hv.x, hv.y, hv.z, hv.w};
#pragma unroll
    for (int c = 0; c < 2; c++) {
      float2 f0 = __half22float2(*(__half2*)&uu[2 * c]);
      float2 f1 = __half22float2(*(__half2*)&uu[2 * c + 1]);
      q[2 * s + c] = ((u32)(quanti(f0.x, inv) & 255)) |
                     ((u32)(quanti(f0.y, inv) & 255) << 8) |
                     ((u32)(quanti(f1.x, inv) & 255) << 16) |
                     ((u32)(quanti(f1.y, inv) & 255) << 24);
    }
  }
  asm volatile("" ::: "memory");
  i8* op = (i8*)h + row * 8192 + bx * 1024 + quad * 8;
#pragma unroll
  for (int s = 0; s < 16; s++) {
    uint2 o = {q[2 * s], q[2 * s + 1]};
    *(uint2*)(op + s * 32) = o;
  }
  if (l15 < 8) {
#pragma unroll
    for (int r = 0; r < 4; r++) {
      long m = m0 + quad * 4 + r;
      atomicAdd(&t2[m * 8 + l15], acc[r]);
    }
  }
}

// ---------- 8-phase pipelined i8 GEMM: C = Aq * Bq^T, BM=256, BK=128 --------
// A: [M] rows stride lda bytes, B: [N] rows stride ldb bytes, K-major i8.
// LDS XOR-swizzle: phys 16B-chunk p at row r holds logical chunk p^(r&7)
// (pre-swizzled global source, linear global_load_lds dest — both-sides).
// Per K-tile t (buf b=t&1), 4 phases:
//   ph1: ds_read A[kk0](MT)+B[kk0](NT); stage B-h0(t+1)->buf b'   | MFMA kk0,mh0
//   ph2: ds_read A[kk1](MT);            stage B-h1(t+1)->buf b'   | MFMA kk0,mh1
//   ph3: ds_read B[kk1](NT);            stage A-h0(t+2)->buf b    | MFMA kk1,mh0
//   ph4: (no reads);                    stage A-h1(t+2)->buf b    | MFMA kk1,mh1
//        + vmcnt(4) [A(t+2) may stay in flight] + barrier.
// Safety: buf b's A region fully read after ph2's lgkmcnt+barrier (A reads
// only in ph1/ph2), B region after ph3 — every stage targets a region whose
// prior readers completed a barrier earlier. Raw s_barrier everywhere in the
// loop (no __syncthreads -> no vmcnt(0) drain).
// MODE 0: *scale+bias+2*t.Bl, GELU, fp16 h store, absmax(h).
// MODE 1: *scale+bias+2*t.Bl, fp32 store; A in CHUNKED col layout
//         (byte (c>>9)*1024 + (c&511), rowstride 8192) -> kb(t) below.
template <int MODE, int BN, int WARPS_M>
__launch_bounds__(512, 2) __global__
    void gemm8p_kernel(const i8* __restrict__ A, const i8* __restrict__ B,
                       int N, int K, int lda, int ldb,
                       const float* __restrict__ bias,
                       const float* __restrict__ tl,   // [M][8] f32
                       const float* __restrict__ Bl,   // [N][8] f32
                       const u32* __restrict__ scales, int sa, int sb,
                       void* __restrict__ outp, u32* __restrict__ hmax) {
  constexpr int WARPS_N = 8 / WARPS_M;
  constexpr int MT = 256 / (16 * WARPS_M);   // m-tiles per wave
  constexpr int NT = BN / (16 * WARPS_N);    // n-tiles per wave
  constexpr int LB = BN / 128;               // B loads per half per thread
  __shared__ __align__(16) i8 As[2][256 * 128];
  __shared__ __align__(16) i8 Bs[2][BN * 128];
  __shared__ u32 bmax;
  int tid = threadIdx.x;
  int lane = tid & 63, wave = tid >> 6;
  int quad = lane >> 4, l15 = lane & 15;
  int wm = (wave % WARPS_M) * (MT * 16);
  int wn = (wave / WARPS_M) * (NT * 16);
  // XCD-bijective swizzle (nwg % 8 == 0 for both grids)
  int nwg = gridDim.x * gridDim.y;
  int lin = blockIdx.y * gridDim.x + blockIdx.x;
  int swb = (lin & 7) * (nwg >> 3) + (lin >> 3);
  int bx = swb % gridDim.x, by = swb / gridDim.x;
  long m0 = (long)by * 256;
  long n0 = (long)bx * BN;
  if (MODE == 0 && tid == 0) bmax = 0u;

  // staging precompute: A-half = 128 rows x 128B = 1024 chunks -> 2/thread;
  // B-half = (BN/2) rows -> LB/thread. chunk c = u*512+tid; row=c>>3;
  // source k-chunk pre-swizzled by (row&7).
  const i8* pA[2];
  int ldsA[2];
#pragma unroll
  for (int u = 0; u < 2; u++) {
    int c = u * 512 + tid;
    int row = c >> 3;
    int swz = ((c & 7) ^ (row & 7)) * 16;
    pA[u] = A + (m0 + row) * lda + swz;
    ldsA[u] = c * 16;
  }
  const i8* pB[LB];
  int ldsB[LB];
#pragma unroll
  for (int u = 0; u < LB; u++) {
    int c = u * 512 + tid;
    int row = c >> 3;
    int swz = ((c & 7) ^ (row & 7)) * 16;
    pB[u] = B + (n0 + row) * ldb + swz;
    ldsB[u] = c * 16;
  }

  auto stageA = [&](int t, int h) {
    int kb = (MODE == 1) ? ((t >> 2) * 1024 + (t & 3) * 128) : (t << 7);
    int bb = t & 1;
#pragma unroll
    for (int u = 0; u < 2; u++)
      ASYNC16(pA[u] + (long)h * 128 * lda + kb,
              &As[bb][h * 16384 + ldsA[u]]);
  };
  auto stageB = [&](int t, int h) {
    int kb = t << 7;
    int bb = t & 1;
#pragma unroll
    for (int u = 0; u < LB; u++)
      ASYNC16(pB[u] + (long)h * (BN / 2) * ldb + kb,
              &Bs[bb][h * (BN / 2) * 128 + ldsB[u]]);
  };

  // fragment-read swizzled chunk byte offsets: chunk = (kk*4+quad)^(l15&7)
  int s0 = (quad ^ (l15 & 7)) * 16;
  int s1 = s0 ^ 64;

  i32x4 acc[MT][NT] = {};
  int NTILES = K >> 7;

  // prologue: tile0 fully + tile1 A-halves; then wait tile0 (4 may fly)
  stageA(0, 0); stageA(0, 1); stageB(0, 0); stageB(0, 1);
  stageA(1, 0); stageA(1, 1);
  VMCNT(4);
  SBAR;

  for (int t = 0; t < NTILES; t++) {
    const i8* Ab = As[t & 1];
    const i8* Bb = Bs[t & 1];
    i32x4 a0[MT], a1[MT], b0[NT], b1[NT];
    // ---- phase 1: read A[kk0]+B[kk0]; stage B-h0(t+1); MFMA kk0, mhalf0
#pragma unroll
    for (int i = 0; i < MT; i++)
      a0[i] = *(const i32x4*)(Ab + (wm + i * 16 + l15) * 128 + s0);
#pragma unroll
    for (int j = 0; j < NT; j++)
      b0[j] = *(const i32x4*)(Bb + (wn + j * 16 + l15) * 128 + s0);
    if (t + 1 < NTILES) stageB(t + 1, 0);
    SBAR;
    LGKM0;
    __builtin_amdgcn_s_setprio(1);
#pragma unroll
    for (int i = 0; i < MT / 2; i++)
#pragma unroll
      for (int j = 0; j < NT; j++)
        acc[i][j] = __builtin_amdgcn_mfma_i32_16x16x64_i8(a0[i], b0[j],
                                                          acc[i][j], 0, 0, 0);
    __builtin_amdgcn_s_setprio(0);
    SBAR;
    // ---- phase 2: read A[kk1]; stage B-h1(t+1); MFMA kk0, mhalf1
#pragma unroll
    for (int i = 0; i < MT; i++)
      a1[i] = *(const i32x4*)(Ab + (wm + i * 16 + l15) * 128 + s1);
    if (t + 1 < NTILES) stageB(t + 1, 1);
    SBAR;
    LGKM0;
    __builtin_amdgcn_s_setprio(1);
#pragma unroll
    for (int i = MT / 2; i < MT; i++)
#pragma unroll
      for (int j = 0; j < NT; j++)
        acc[i][j] = __builtin_amdgcn_mfma_i32_16x16x64_i8(a0[i], b0[j],
                                                          acc[i][j], 0, 0, 0);
    __builtin_amdgcn_s_setprio(0);
    SBAR;
    // ---- phase 3: read B[kk1]; stage A-h0(t+2); MFMA kk1, mhalf0
#pragma unroll
    for (int j = 0; j < NT; j++)
      b1[j] = *(const i32x4*)(Bb + (wn + j * 16 + l15) * 128 + s1);
    if (t + 2 < NTILES) stageA(t + 2, 0);
    SBAR;
    LGKM0;
    __builtin_amdgcn_s_setprio(1);
#pragma unroll
    for (int i = 0; i < MT / 2; i++)
#pragma unroll
      for (int j = 0; j < NT; j++)
        acc[i][j] = __builtin_amdgcn_mfma_i32_16x16x64_i8(a1[i], b1[j],
                                                          acc[i][j], 0, 0, 0);
    __builtin_amdgcn_s_setprio(0);
    SBAR;
    // ---- phase 4: stage A-h1(t+2); MFMA kk1, mhalf1; counted vmcnt
    if (t + 2 < NTILES) stageA(t + 2, 1);
    SBAR;
    __builtin_amdgcn_s_setprio(1);
#pragma unroll
    for (int i = MT / 2; i < MT; i++)
#pragma unroll
      for (int j = 0; j < NT; j++)
        acc[i][j] = __builtin_amdgcn_mfma_i32_16x16x64_i8(a1[i], b1[j],
                                                          acc[i][j], 0, 0, 0);
    __builtin_amdgcn_s_setprio(0);
    if (t + 2 < NTILES) {
      VMCNT(4);   // allow A(t+2)'s 4 loads to stay in flight
    } else {
      VMCNT(0);   // tail: everything must land
    }
    SBAR;
  }

  // epilogue
  float scale = load_scale(scales + sa) * load_scale(scales + sb);
  float biasv[NT];
  float4 bl0[NT], bl1[NT];
#pragma unroll
  for (int j = 0; j < NT; j++) {
    long n = n0 + wn + j * 16 + l15;
    biasv[j] = bias[n];
    bl0[j] = ((const float4*)(Bl + n * 8))[0];
    bl1[j] = ((const float4*)(Bl + n * 8))[1];
  }
  float lmax = 0.0f;
#pragma unroll
  for (int i = 0; i < MT; i++) {
#pragma unroll
    for (int r = 0; r < 4; r++) {
      long m = m0 + wm + i * 16 + quad * 4 + r;
      float4 t0 = ((const float4*)(tl + m * 8))[0];
      float4 t1v = ((const float4*)(tl + m * 8))[1];
#pragma unroll
      for (int j = 0; j < NT; j++) {
        long n = n0 + wn + j * 16 + l15;
        float lora = t0.x * bl0[j].x + t0.y * bl0[j].y + t0.z * bl0[j].z +
                     t0.w * bl0[j].w + t1v.x * bl1[j].x + t1v.y * bl1[j].y +
                     t1v.z * bl1[j].z + t1v.w * bl1[j].w;
        float v = (float)acc[i][j][r] * scale + biasv[j] + 2.0f * lora;
        if (MODE == 0) {
          float hv = gelu_erf(v);
          __half hh = __float2half_rn(hv);
          ((u16*)outp)[m * N + n] = *(u16*)&hh;
          lmax = fmaxf(lmax, fabsf(hv));
        } else {
          ((float*)outp)[m * N + n] = v;
        }
      }
    }
  }
  if (MODE == 0) {
    atomicMax(&bmax, __float_as_uint(lmax));
    __syncthreads();
    if (tid == 0) atomicMax(hmax, bmax);
  }
}

extern "C" void kernel_launch(void* const* d_in, const int* in_sizes, int n_in,
                              void* d_out, int out_size, void* d_ws,
                              size_t ws_size, hipStream_t stream) {
  const float* x = (const float*)d_in[0];    // [8192][1024]
  const float* Wfc = (const float*)d_in[1];  // [4096][1024]
  const float* bfc = (const float*)d_in[2];  // [4096]
  const float* Afc = (const float*)d_in[3];  // [8][1024]
  const float* Bfc = (const float*)d_in[4];  // [4096][8]
  const float* Wpr = (const float*)d_in[5];  // [1024][4096]
  const float* bpr = (const float*)d_in[6];  // [1024]
  const float* Apr = (const float*)d_in[7];  // [8][4096]
  const float* Bpr = (const float*)d_in[8];  // [1024][8]
  float* out = (float*)d_out;                // fp32 [8192][1024]

  char* w = (char*)d_ws;
  u32* scales = (u32*)w;                   // 4 slots (fp32 bits): x, Wfc, Wpr, h
  float* t1 = (float*)(w + 256);           // [8192][8]
  float* t2 = (float*)(w + 256 + 262144);  // [8192][8]
  i8* xq = (i8*)(w + 524544);              // [8192][1024] i8
  f16* aprh = (f16*)(w + 8913152);         // [16][4096] fp16 (in xq..wq1 gap)
  i8* wq1 = (i8*)(w + 9437184);            // [4096][1024] i8
  i8* wq2 = (i8*)(w + 13631488);           // [1024][4096] i8
  u16* hq = (u16*)(w + 17825792);          // [8192][4096] fp16 h; i8 in place
  if (ws_size < 84934656) return;          // need ~81 MiB scratch

  hipMemsetAsync(scales, 0, 256, stream);
  hipMemsetAsync(t2, 0, 262144, stream);   // t2 accumulated via atomicAdd
  conv_a16_kernel<<<64, 256, 0, stream>>>(Apr, aprh);
  absmax_kernel<<<1024, 256, 0, stream>>>(x, 8192 * 1024 / 4, scales + 0);
  absmax_kernel<<<512, 256, 0, stream>>>(Wfc, 4096 * 1024 / 4, scales + 1);
  absmax_kernel<<<512, 256, 0, stream>>>(Wpr, 4096 * 1024 / 4, scales + 2);
  quant_x_t1_kernel<<<8192, 256, 0, stream>>>(x, Afc, scales + 0, xq, t1);
  quant_w_kernel<<<256, 256, 0, stream>>>(Wfc, 4096 * 1024 / 16, scales + 1,
                                          wq1);
  quant_w_kernel<<<256, 256, 0, stream>>>(Wpr, 4096 * 1024 / 16, scales + 2,
                                          wq2);
  // gemm1: 8192x4096, K=1024, BM=256 BN=256, grid (16,32)=512 (%8==0)
  gemm8p_kernel<0, 256, 2><<<dim3(16, 32), 512, 0, stream>>>(
      xq, wq1, 4096, 1024, 1024, 1024, bfc, t1, Bfc, scales, 0, 1, hq,
      scales + 3);
  quant_h_t2_fused<<<dim3(8, 128), 256, 0, stream>>>(hq, aprh, scales + 3, t2);
  // gemm2: 8192x1024, K=4096, BM=256 BN=128, grid (8,32)=256 (%8==0)
  gemm8p_kernel<1, 128, 4><<<dim3(8, 32), 512, 0, stream>>>(
      (const i8*)hq, wq2, 1024, 4096, 8192, 4096, bpr, t2, Bpr, scales, 3, 2,
      out, nullptr);
}

// Round 3
// 306.833 us; speedup vs baseline: 1.2587x; 1.0458x over previous
//
#include <hip/hip_runtime.h>
#include <hip/hip_bf16.h>
#include <hip/hip_fp16.h>
#include <math.h>

// QAT GPT2 MLP + LoRA on MI355X — fp32 in/out.
// Round 8: kill the hidden hog. Cross-round accounting shows quant_x_t1
// (block-per-row, A_fc re-read 256MB L2, 48 shfl chains) has been ~60-78us,
// hiding under every top-5 cutoff. Replaced with quant_x_t1_fused: wave owns
// 16 rows x 512 cols; each 32B fp32 load feeds the exact i8 quantizer
// (bit-identical xq) AND an fp16 MFMA fragment for t1 = x.Afc^T (HW
// k-reduction, no shuffles/barriers; same scheme as the verified t2 path).
// Afc pre-converted to fp16 [16][1024] rows 8-15 zero; t1 via atomicAdd
// (t1+t2 zeroed in one memset). GEMMs: 8-phase schedule kept; dropped the
// sched_barrier(0) pin from LGKM0 (ds_reads are compiler-visible loads;
// rule #18 doesn't apply — let the scheduler overlap addr math with MFMA).
// Round-7 gemm1 130->80.5us confirmed; round-6 fused t2 kept.

typedef unsigned short u16;
typedef unsigned int u32;
typedef signed char i8;
typedef int i32x4 __attribute__((ext_vector_type(4)));
typedef _Float16 f16;
typedef f16 f16x8 __attribute__((ext_vector_type(8)));
typedef float f32x4 __attribute__((ext_vector_type(4)));

#define ASYNC16(gp, lp)                                                        \
  __builtin_amdgcn_global_load_lds(                                            \
      (__attribute__((address_space(1))) void*)(gp),                           \
      (__attribute__((address_space(3))) void*)(lp), 16, 0, 0)

#define VMCNT(N) asm volatile("s_waitcnt vmcnt(" #N ")" ::: "memory")
#define LGKM0 asm volatile("s_waitcnt lgkmcnt(0)" ::: "memory")
#define SBAR __builtin_amdgcn_s_barrier()

// quantize to int: q = clip(rint(v/s), -128, 127)
__device__ __forceinline__ int quanti(float v, float inv) {
  float q = rintf(v * inv);
  q = fminf(fmaxf(q, -128.0f), 127.0f);
  return (int)q;
}

__device__ __forceinline__ u32 pack4(float4 v, float inv) {
  return ((u32)(quanti(v.x, inv) & 255)) |
         ((u32)(quanti(v.y, inv) & 255) << 8) |
         ((u32)(quanti(v.z, inv) & 255) << 16) |
         ((u32)(quanti(v.w, inv) & 255) << 24);
}

__device__ __forceinline__ float load_scale(const u32* slot) {
  return fmaxf(__uint_as_float(*slot) * (1.0f / 127.0f), 1e-8f);
}

// exact-erf GELU via Abramowitz-Stegun 7.1.26 (|erf err| <= 1.5e-7)
__device__ __forceinline__ float gelu_erf(float v) {
  float z = fabsf(v) * 0.70710678118654752f;
  float t = __builtin_amdgcn_rcpf(fmaf(0.3275911f, z, 1.0f));
  float poly =
      t * fmaf(t,
               fmaf(t,
                    fmaf(t, fmaf(t, 1.061405429f, -1.453152027f),
                         1.421413741f),
                    -0.284496736f),
               0.254829592f);
  float e = fmaf(-poly, exp2f(-z * z * 1.4426950408889634f), 1.0f);
  return 0.5f * v * fmaf(copysignf(e, v), 1.0f, 1.0f);
}

// -------------------- absmax over fp32 tensor (float4 grid-stride) ----------
__global__ void absmax_kernel(const float* __restrict__ x, int n4,
                              u32* __restrict__ slot) {
  float m = 0.0f;
  int stride = gridDim.x * blockDim.x;
  for (int i = blockIdx.x * blockDim.x + threadIdx.x; i < n4; i += stride) {
    float4 v = ((const float4*)x)[i];
    m = fmaxf(m, fmaxf(fmaxf(fabsf(v.x), fabsf(v.y)),
                       fmaxf(fabsf(v.z), fabsf(v.w))));
  }
#pragma unroll
  for (int off = 32; off > 0; off >>= 1) m = fmaxf(m, __shfl_down(m, off));
  __shared__ float wmax[4];
  int lane = threadIdx.x & 63, wave = threadIdx.x >> 6;
  if (lane == 0) wmax[wave] = m;
  __syncthreads();
  if (threadIdx.x == 0) {
    m = fmaxf(fmaxf(wmax[0], wmax[1]), fmaxf(wmax[2], wmax[3]));
    atomicMax(slot, __float_as_uint(m));  // positive floats: bit-monotone
  }
}

// ---------------- quantize W (fp32 in, packed i8 out) -----------------------
__global__ void quant_w_kernel(const float* __restrict__ w, int n16,
                               const u32* __restrict__ slot,
                               i8* __restrict__ q) {
  float inv = 1.0f / load_scale(slot);
  int stride = gridDim.x * blockDim.x;
  for (int i = blockIdx.x * blockDim.x + threadIdx.x; i < n16; i += stride) {
    const float4* src = (const float4*)w + i * 4;
    u32 pk[4];
#pragma unroll
    for (int c = 0; c < 4; c++) pk[c] = pack4(src[c], inv);
    uint4 o = {pk[0], pk[1], pk[2], pk[3]};
    ((uint4*)q)[i] = o;
  }
}

// ---- convert A [8][ncols] fp32 -> [16][ncols] fp16, rows 8-15 zero ---------
__global__ void conv_a16_kernel(const float* __restrict__ A,
                                f16* __restrict__ Ah, int ncols) {
  int i = blockIdx.x * blockDim.x + threadIdx.x;  // one f16x8 per thread
  int base = i * 8;
  if (base >= 16 * ncols) return;
  if (base < 8 * ncols) {
    float4 v0 = ((const float4*)(A + base))[0];
    float4 v1 = ((const float4*)(A + base))[1];
    f16x8 o = {(f16)v0.x, (f16)v0.y, (f16)v0.z, (f16)v0.w,
               (f16)v1.x, (f16)v1.y, (f16)v1.z, (f16)v1.w};
    *(f16x8*)(Ah + base) = o;
  } else {
    f16x8 z = {};
    *(f16x8*)(Ah + base) = z;
  }
}

// ---- fused: quantize x (fp32 -> i8, exact) + t1 = x.Afc^T via fp16 MFMA ----
// Wave owns rows [m0,m0+16) x cols [k0,k0+512). A-frag: lane(quad,l15) holds
// x[m=l15][k=quad*8..+7] converted fp32->fp16 (t1 path only; xq quantized
// from the original fp32 -> bit-identical to the old kernel). B-operand:
// Ah[16][1024] fp16, n=l15 = LoRA rank, rows 8-15 zero. C/D: col=lane&15(=r),
// row=quad*4+reg [m89]. t1 accumulated with atomicAdd (k-split bx in [0,2)).
__launch_bounds__(256) __global__
    void quant_x_t1_fused(const float* __restrict__ x,   // [8192][1024]
                          const f16* __restrict__ Ah,    // [16][1024]
                          const u32* __restrict__ slot,
                          i8* __restrict__ xq,           // [8192][1024]
                          float* __restrict__ t1) {      // [8192][8], zeroed
  int tid = threadIdx.x;
  int lane = tid & 63, wave = tid >> 6;
  int quad = lane >> 4, l15 = lane & 15;
  int bx = blockIdx.x;                       // k-chunk [0,2)
  long m0 = (long)blockIdx.y * 64 + wave * 16;
  long row = m0 + l15;
  int k0 = bx * 512;
  float inv = 1.0f / load_scale(slot);

  const float* xp = x + row * 1024 + k0 + quad * 8;
  const f16* ap = Ah + l15 * 1024 + k0 + quad * 8;
  i8* op = xq + row * 1024 + k0 + quad * 8;
  f32x4 acc = {0.0f, 0.0f, 0.0f, 0.0f};
#pragma unroll
  for (int s = 0; s < 16; s++) {
    float4 v0 = ((const float4*)(xp + s * 32))[0];
    float4 v1 = ((const float4*)(xp + s * 32))[1];
    f16x8 af = {(f16)v0.x, (f16)v0.y, (f16)v0.z, (f16)v0.w,
                (f16)v1.x, (f16)v1.y, (f16)v1.z, (f16)v1.w};
    f16x8 bf = *(const f16x8*)(ap + s * 32);
    acc = __builtin_amdgcn_mfma_f32_16x16x32_f16(af, bf, acc, 0, 0, 0);
    uint2 o = {pack4(v0, inv), pack4(v1, inv)};
    *(uint2*)(op + s * 32) = o;
  }
  if (l15 < 8) {
#pragma unroll
    for (int r = 0; r < 4; r++) {
      long m = m0 + quad * 4 + r;
      atomicAdd(&t1[m * 8 + l15], acc[r]);
    }
  }
}

// ---- fused: quantize h (fp16 -> i8 in place, chunked) + t2 = h.A^T via MFMA
__launch_bounds__(256) __global__
    void quant_h_t2_fused(u16* __restrict__ h,        // [8192][4096] fp16
                          const f16* __restrict__ Ah, // [16][4096]
                          const u32* __restrict__ slot,
                          float* __restrict__ t2) {   // [8192][8], pre-zeroed
  int tid = threadIdx.x;
  int lane = tid & 63, wave = tid >> 6;
  int quad = lane >> 4, l15 = lane & 15;
  int bx = blockIdx.x;                       // k-chunk index [0,8)
  long m0 = (long)blockIdx.y * 64 + wave * 16;
  long row = m0 + l15;
  int k0 = bx * 512;
  float inv = 1.0f / load_scale(slot);

  const u16* hp = h + row * 4096 + k0 + quad * 8;
  const f16* ap = Ah + l15 * 4096 + k0 + quad * 8;
  f32x4 acc = {0.0f, 0.0f, 0.0f, 0.0f};
  u32 q[32];
#pragma unroll
  for (int s = 0; s < 16; s++) {
    uint4 hv = *(const uint4*)(hp + s * 32);   // 8 fp16 of h
    f16x8 af = *(const f16x8*)&hv;
    f16x8 bf = *(const f16x8*)(ap + s * 32);
    acc = __builtin_amdgcn_mfma_f32_16x16x32_f16(af, bf, acc, 0, 0, 0);
    u32 uu[4] = {hv.x, hv.y, hv.z, hv.w};
#pragma unroll
    for (int c = 0; c < 2; c++) {
      float2 f0 = __half22float2(*(__half2*)&uu[2 * c]);
      float2 f1 = __half22float2(*(__half2*)&uu[2 * c + 1]);
      q[2 * s + c] = ((u32)(quanti(f0.x, inv) & 255)) |
                     ((u32)(quanti(f0.y, inv) & 255) << 8) |
                     ((u32)(quanti(f1.x, inv) & 255) << 16) |
                     ((u32)(quanti(f1.y, inv) & 255) << 24);
    }
  }
  asm volatile("" ::: "memory");
  i8* op = (i8*)h + row * 8192 + bx * 1024 + quad * 8;
#pragma unroll
  for (int s = 0; s < 16; s++) {
    uint2 o = {q[2 * s], q[2 * s + 1]};
    *(uint2*)(op + s * 32) = o;
  }
  if (l15 < 8) {
#pragma unroll
    for (int r = 0; r < 4; r++) {
      long m = m0 + quad * 4 + r;
      atomicAdd(&t2[m * 8 + l15], acc[r]);
    }
  }
}

// ---------- 8-phase pipelined i8 GEMM: C = Aq * Bq^T, BM=256, BK=128 --------
// (see round-7 comment block for the phase/safety derivation)
template <int MODE, int BN, int WARPS_M>
__launch_bounds__(512, 2) __global__
    void gemm8p_kernel(const i8* __restrict__ A, const i8* __restrict__ B,
                       int N, int K, int lda, int ldb,
                       const float* __restrict__ bias,
                       const float* __restrict__ tl,   // [M][8] f32
                       const float* __restrict__ Bl,   // [N][8] f32
                       const u32* __restrict__ scales, int sa, int sb,
                       void* __restrict__ outp, u32* __restrict__ hmax) {
  constexpr int WARPS_N = 8 / WARPS_M;
  constexpr int MT = 256 / (16 * WARPS_M);   // m-tiles per wave
  constexpr int NT = BN / (16 * WARPS_N);    // n-tiles per wave
  constexpr int LB = BN / 128;               // B loads per half per thread
  __shared__ __align__(16) i8 As[2][256 * 128];
  __shared__ __align__(16) i8 Bs[2][BN * 128];
  __shared__ u32 bmax;
  int tid = threadIdx.x;
  int lane = tid & 63, wave = tid >> 6;
  int quad = lane >> 4, l15 = lane & 15;
  int wm = (wave % WARPS_M) * (MT * 16);
  int wn = (wave / WARPS_M) * (NT * 16);
  // XCD-bijective swizzle (nwg % 8 == 0 for both grids)
  int nwg = gridDim.x * gridDim.y;
  int lin = blockIdx.y * gridDim.x + blockIdx.x;
  int swb = (lin & 7) * (nwg >> 3) + (lin >> 3);
  int bx = swb % gridDim.x, by = swb / gridDim.x;
  long m0 = (long)by * 256;
  long n0 = (long)bx * BN;
  if (MODE == 0 && tid == 0) bmax = 0u;

  const i8* pA[2];
  int ldsA[2];
#pragma unroll
  for (int u = 0; u < 2; u++) {
    int c = u * 512 + tid;
    int row = c >> 3;
    int swz = ((c & 7) ^ (row & 7)) * 16;
    pA[u] = A + (m0 + row) * lda + swz;
    ldsA[u] = c * 16;
  }
  const i8* pB[LB];
  int ldsB[LB];
#pragma unroll
  for (int u = 0; u < LB; u++) {
    int c = u * 512 + tid;
    int row = c >> 3;
    int swz = ((c & 7) ^ (row & 7)) * 16;
    pB[u] = B + (n0 + row) * ldb + swz;
    ldsB[u] = c * 16;
  }

  auto stageA = [&](int t, int h) {
    int kb = (MODE == 1) ? ((t >> 2) * 1024 + (t & 3) * 128) : (t << 7);
    int bb = t & 1;
#pragma unroll
    for (int u = 0; u < 2; u++)
      ASYNC16(pA[u] + (long)h * 128 * lda + kb,
              &As[bb][h * 16384 + ldsA[u]]);
  };
  auto stageB = [&](int t, int h) {
    int kb = t << 7;
    int bb = t & 1;
#pragma unroll
    for (int u = 0; u < LB; u++)
      ASYNC16(pB[u] + (long)h * (BN / 2) * ldb + kb,
              &Bs[bb][h * (BN / 2) * 128 + ldsB[u]]);
  };

  int s0 = (quad ^ (l15 & 7)) * 16;
  int s1 = s0 ^ 64;

  i32x4 acc[MT][NT] = {};
  int NTILES = K >> 7;

  // prologue: tile0 fully + tile1 A-halves; then wait tile0 (4 may fly)
  stageA(0, 0); stageA(0, 1); stageB(0, 0); stageB(0, 1);
  stageA(1, 0); stageA(1, 1);
  VMCNT(4);
  SBAR;

  for (int t = 0; t < NTILES; t++) {
    const i8* Ab = As[t & 1];
    const i8* Bb = Bs[t & 1];
    i32x4 a0[MT], a1[MT], b0[NT], b1[NT];
    // ---- phase 1: read A[kk0]+B[kk0]; stage B-h0(t+1); MFMA kk0, mhalf0
#pragma unroll
    for (int i = 0; i < MT; i++)
      a0[i] = *(const i32x4*)(Ab + (wm + i * 16 + l15) * 128 + s0);
#pragma unroll
    for (int j = 0; j < NT; j++)
      b0[j] = *(const i32x4*)(Bb + (wn + j * 16 + l15) * 128 + s0);
    if (t + 1 < NTILES) stageB(t + 1, 0);
    SBAR;
    LGKM0;
    __builtin_amdgcn_s_setprio(1);
#pragma unroll
    for (int i = 0; i < MT / 2; i++)
#pragma unroll
      for (int j = 0; j < NT; j++)
        acc[i][j] = __builtin_amdgcn_mfma_i32_16x16x64_i8(a0[i], b0[j],
                                                          acc[i][j], 0, 0, 0);
    __builtin_amdgcn_s_setprio(0);
    SBAR;
    // ---- phase 2: read A[kk1]; stage B-h1(t+1); MFMA kk0, mhalf1
#pragma unroll
    for (int i = 0; i < MT; i++)
      a1[i] = *(const i32x4*)(Ab + (wm + i * 16 + l15) * 128 + s1);
    if (t + 1 < NTILES) stageB(t + 1, 1);
    SBAR;
    LGKM0;
    __builtin_amdgcn_s_setprio(1);
#pragma unroll
    for (int i = MT / 2; i < MT; i++)
#pragma unroll
      for (int j = 0; j < NT; j++)
        acc[i][j] = __builtin_amdgcn_mfma_i32_16x16x64_i8(a0[i], b0[j],
                                                          acc[i][j], 0, 0, 0);
    __builtin_amdgcn_s_setprio(0);
    SBAR;
    // ---- phase 3: read B[kk1]; stage A-h0(t+2); MFMA kk1, mhalf0
#pragma unroll
    for (int j = 0; j < NT; j++)
      b1[j] = *(const i32x4*)(Bb + (wn + j * 16 + l15) * 128 + s1);
    if (t + 2 < NTILES) stageA(t + 2, 0);
    SBAR;
    LGKM0;
    __builtin_amdgcn_s_setprio(1);
#pragma unroll
    for (int i = 0; i < MT / 2; i++)
#pragma unroll
      for (int j = 0; j < NT; j++)
        acc[i][j] = __builtin_amdgcn_mfma_i32_16x16x64_i8(a1[i], b1[j],
                                                          acc[i][j], 0, 0, 0);
    __builtin_amdgcn_s_setprio(0);
    SBAR;
    // ---- phase 4: stage A-h1(t+2); MFMA kk1, mhalf1; counted vmcnt
    if (t + 2 < NTILES) stageA(t + 2, 1);
    SBAR;
    __builtin_amdgcn_s_setprio(1);
#pragma unroll
    for (int i = MT / 2; i < MT; i++)
#pragma unroll
      for (int j = 0; j < NT; j++)
        acc[i][j] = __builtin_amdgcn_mfma_i32_16x16x64_i8(a1[i], b1[j],
                                                          acc[i][j], 0, 0, 0);
    __builtin_amdgcn_s_setprio(0);
    if (t + 2 < NTILES) {
      VMCNT(4);   // allow A(t+2)'s 4 loads to stay in flight
    } else {
      VMCNT(0);   // tail: everything must land
    }
    SBAR;
  }

  // epilogue
  float scale = load_scale(scales + sa) * load_scale(scales + sb);
  float biasv[NT];
  float4 bl0[NT], bl1[NT];
#pragma unroll
  for (int j = 0; j < NT; j++) {
    long n = n0 + wn + j * 16 + l15;
    biasv[j] = bias[n];
    bl0[j] = ((const float4*)(Bl + n * 8))[0];
    bl1[j] = ((const float4*)(Bl + n * 8))[1];
  }
  float lmax = 0.0f;
#pragma unroll
  for (int i = 0; i < MT; i++) {
#pragma unroll
    for (int r = 0; r < 4; r++) {
      long m = m0 + wm + i * 16 + quad * 4 + r;
      float4 t0 = ((const float4*)(tl + m * 8))[0];
      float4 t1v = ((const float4*)(tl + m * 8))[1];
#pragma unroll
      for (int j = 0; j < NT; j++) {
        long n = n0 + wn + j * 16 + l15;
        float lora = t0.x * bl0[j].x + t0.y * bl0[j].y + t0.z * bl0[j].z +
                     t0.w * bl0[j].w + t1v.x * bl1[j].x + t1v.y * bl1[j].y +
                     t1v.z * bl1[j].z + t1v.w * bl1[j].w;
        float v = (float)acc[i][j][r] * scale + biasv[j] + 2.0f * lora;
        if (MODE == 0) {
          float hv = gelu_erf(v);
          __half hh = __float2half_rn(hv);
          ((u16*)outp)[m * N + n] = *(u16*)&hh;
          lmax = fmaxf(lmax, fabsf(hv));
        } else {
          ((float*)outp)[m * N + n] = v;
        }
      }
    }
  }
  if (MODE == 0) {
    atomicMax(&bmax, __float_as_uint(lmax));
    __syncthreads();
    if (tid == 0) atomicMax(hmax, bmax);
  }
}

extern "C" void kernel_launch(void* const* d_in, const int* in_sizes, int n_in,
                              void* d_out, int out_size, void* d_ws,
                              size_t ws_size, hipStream_t stream) {
  const float* x = (const float*)d_in[0];    // [8192][1024]
  const float* Wfc = (const float*)d_in[1];  // [4096][1024]
  const float* bfc = (const float*)d_in[2];  // [4096]
  const float* Afc = (const float*)d_in[3];  // [8][1024]
  const float* Bfc = (const float*)d_in[4];  // [4096][8]
  const float* Wpr = (const float*)d_in[5];  // [1024][4096]
  const float* bpr = (const float*)d_in[6];  // [1024]
  const float* Apr = (const float*)d_in[7];  // [8][4096]
  const float* Bpr = (const float*)d_in[8];  // [1024][8]
  float* out = (float*)d_out;                // fp32 [8192][1024]

  char* w = (char*)d_ws;
  u32* scales = (u32*)w;                   // 4 slots (fp32 bits): x, Wfc, Wpr, h
  float* t1 = (float*)(w + 256);           // [8192][8]
  float* t2 = (float*)(w + 256 + 262144);  // [8192][8]
  i8* xq = (i8*)(w + 524544);              // [8192][1024] i8
  f16* aprh = (f16*)(w + 8913152);         // [16][4096] fp16
  f16* afch = (f16*)(w + 9175040);         // [16][1024] fp16 (gap before wq1)
  i8* wq1 = (i8*)(w + 9437184);            // [4096][1024] i8
  i8* wq2 = (i8*)(w + 13631488);           // [1024][4096] i8
  u16* hq = (u16*)(w + 17825792);          // [8192][4096] fp16 h; i8 in place
  if (ws_size < 84934656) return;          // need ~81 MiB scratch

  hipMemsetAsync(w, 0, 524544, stream);    // scales + t1 + t2 (atomicAdd'd)
  conv_a16_kernel<<<32, 256, 0, stream>>>(Apr, aprh, 4096);
  conv_a16_kernel<<<8, 256, 0, stream>>>(Afc, afch, 1024);
  absmax_kernel<<<1024, 256, 0, stream>>>(x, 8192 * 1024 / 4, scales + 0);
  absmax_kernel<<<512, 256, 0, stream>>>(Wfc, 4096 * 1024 / 4, scales + 1);
  absmax_kernel<<<512, 256, 0, stream>>>(Wpr, 4096 * 1024 / 4, scales + 2);
  quant_x_t1_fused<<<dim3(2, 128), 256, 0, stream>>>(x, afch, scales + 0, xq,
                                                     t1);
  quant_w_kernel<<<256, 256, 0, stream>>>(Wfc, 4096 * 1024 / 16, scales + 1,
                                          wq1);
  quant_w_kernel<<<256, 256, 0, stream>>>(Wpr, 4096 * 1024 / 16, scales + 2,
                                          wq2);
  // gemm1: 8192x4096, K=1024, BM=256 BN=256, grid (16,32)=512 (%8==0)
  gemm8p_kernel<0, 256, 2><<<dim3(16, 32), 512, 0, stream>>>(
      xq, wq1, 4096, 1024, 1024, 1024, bfc, t1, Bfc, scales, 0, 1, hq,
      scales + 3);
  quant_h_t2_fused<<<dim3(8, 128), 256, 0, stream>>>(hq, aprh, scales + 3, t2);
  // gemm2: 8192x1024, K=4096, BM=256 BN=128, grid (8,32)=256 (%8==0)
  gemm8p_kernel<1, 128, 4><<<dim3(8, 32), 512, 0, stream>>>(
      (const i8*)hq, wq2, 1024, 4096, 8192, 4096, bpr, t2, Bpr, scales, 3, 2,
      out, nullptr);
}

// Round 4
// 304.707 us; speedup vs baseline: 1.2675x; 1.0070x over previous
//
#include <hip/hip_runtime.h>
#include <hip/hip_bf16.h>
#include <hip/hip_fp16.h>
#include <math.h>

// QAT GPT2 MLP + LoRA on MI355X — fp32 in/out.
// Round 9: the 256-tile 8-phase GEMM ran 1 block/CU (131KB LDS) — 8 waves
// lockstepped on one barrier chain, MfmaUtil 17%, nothing physical saturated.
// m114: cross-block wave overlap (2+ independent blocks/CU) is what actually
// fills pipeline gaps. Restructure both GEMMs to BM=BN=128, BK=128 (proven
// swizzle/staging/pipeline unchanged), 256 thr / 4 waves (2Mx2N, MT=NT=4),
// LDS 64KB -> 2 INDEPENDENT blocks/CU. Phases per K-tile: ph1 {read a0,a1,b0
// | stage B(t+1)} MFMA(a0,b0); ph2 {read b1 | stage A(t+2) into consumed buf}
// MFMA(a1,b1) + counted vmcnt(4). gemm2 grid 8x64=512 = all-resident.
// Round-8 fused quant_x_t1 + round-6 fused quant_h_t2 kept.

typedef unsigned short u16;
typedef unsigned int u32;
typedef signed char i8;
typedef int i32x4 __attribute__((ext_vector_type(4)));
typedef _Float16 f16;
typedef f16 f16x8 __attribute__((ext_vector_type(8)));
typedef float f32x4 __attribute__((ext_vector_type(4)));

#define ASYNC16(gp, lp)                                                        \
  __builtin_amdgcn_global_load_lds(                                            \
      (__attribute__((address_space(1))) void*)(gp),                           \
      (__attribute__((address_space(3))) void*)(lp), 16, 0, 0)

#define VMCNT(N) asm volatile("s_waitcnt vmcnt(" #N ")" ::: "memory")
#define LGKM0 asm volatile("s_waitcnt lgkmcnt(0)" ::: "memory")
#define SBAR __builtin_amdgcn_s_barrier()

// quantize to int: q = clip(rint(v/s), -128, 127)
__device__ __forceinline__ int quanti(float v, float inv) {
  float q = rintf(v * inv);
  q = fminf(fmaxf(q, -128.0f), 127.0f);
  return (int)q;
}

__device__ __forceinline__ u32 pack4(float4 v, float inv) {
  return ((u32)(quanti(v.x, inv) & 255)) |
         ((u32)(quanti(v.y, inv) & 255) << 8) |
         ((u32)(quanti(v.z, inv) & 255) << 16) |
         ((u32)(quanti(v.w, inv) & 255) << 24);
}

__device__ __forceinline__ float load_scale(const u32* slot) {
  return fmaxf(__uint_as_float(*slot) * (1.0f / 127.0f), 1e-8f);
}

// exact-erf GELU via Abramowitz-Stegun 7.1.26 (|erf err| <= 1.5e-7)
__device__ __forceinline__ float gelu_erf(float v) {
  float z = fabsf(v) * 0.70710678118654752f;
  float t = __builtin_amdgcn_rcpf(fmaf(0.3275911f, z, 1.0f));
  float poly =
      t * fmaf(t,
               fmaf(t,
                    fmaf(t, fmaf(t, 1.061405429f, -1.453152027f),
                         1.421413741f),
                    -0.284496736f),
               0.254829592f);
  float e = fmaf(-poly, exp2f(-z * z * 1.4426950408889634f), 1.0f);
  return 0.5f * v * fmaf(copysignf(e, v), 1.0f, 1.0f);
}

// -------------------- absmax over fp32 tensor (float4 grid-stride) ----------
__global__ void absmax_kernel(const float* __restrict__ x, int n4,
                              u32* __restrict__ slot) {
  float m = 0.0f;
  int stride = gridDim.x * blockDim.x;
  for (int i = blockIdx.x * blockDim.x + threadIdx.x; i < n4; i += stride) {
    float4 v = ((const float4*)x)[i];
    m = fmaxf(m, fmaxf(fmaxf(fabsf(v.x), fabsf(v.y)),
                       fmaxf(fabsf(v.z), fabsf(v.w))));
  }
#pragma unroll
  for (int off = 32; off > 0; off >>= 1) m = fmaxf(m, __shfl_down(m, off));
  __shared__ float wmax[4];
  int lane = threadIdx.x & 63, wave = threadIdx.x >> 6;
  if (lane == 0) wmax[wave] = m;
  __syncthreads();
  if (threadIdx.x == 0) {
    m = fmaxf(fmaxf(wmax[0], wmax[1]), fmaxf(wmax[2], wmax[3]));
    atomicMax(slot, __float_as_uint(m));  // positive floats: bit-monotone
  }
}

// ---------------- quantize W (fp32 in, packed i8 out) -----------------------
__global__ void quant_w_kernel(const float* __restrict__ w, int n16,
                               const u32* __restrict__ slot,
                               i8* __restrict__ q) {
  float inv = 1.0f / load_scale(slot);
  int stride = gridDim.x * blockDim.x;
  for (int i = blockIdx.x * blockDim.x + threadIdx.x; i < n16; i += stride) {
    const float4* src = (const float4*)w + i * 4;
    u32 pk[4];
#pragma unroll
    for (int c = 0; c < 4; c++) pk[c] = pack4(src[c], inv);
    uint4 o = {pk[0], pk[1], pk[2], pk[3]};
    ((uint4*)q)[i] = o;
  }
}

// ---- convert A [8][ncols] fp32 -> [16][ncols] fp16, rows 8-15 zero ---------
__global__ void conv_a16_kernel(const float* __restrict__ A,
                                f16* __restrict__ Ah, int ncols) {
  int i = blockIdx.x * blockDim.x + threadIdx.x;  // one f16x8 per thread
  int base = i * 8;
  if (base >= 16 * ncols) return;
  if (base < 8 * ncols) {
    float4 v0 = ((const float4*)(A + base))[0];
    float4 v1 = ((const float4*)(A + base))[1];
    f16x8 o = {(f16)v0.x, (f16)v0.y, (f16)v0.z, (f16)v0.w,
               (f16)v1.x, (f16)v1.y, (f16)v1.z, (f16)v1.w};
    *(f16x8*)(Ah + base) = o;
  } else {
    f16x8 z = {};
    *(f16x8*)(Ah + base) = z;
  }
}

// ---- fused: quantize x (fp32 -> i8, exact) + t1 = x.Afc^T via fp16 MFMA ----
__launch_bounds__(256) __global__
    void quant_x_t1_fused(const float* __restrict__ x,   // [8192][1024]
                          const f16* __restrict__ Ah,    // [16][1024]
                          const u32* __restrict__ slot,
                          i8* __restrict__ xq,           // [8192][1024]
                          float* __restrict__ t1) {      // [8192][8], zeroed
  int tid = threadIdx.x;
  int lane = tid & 63, wave = tid >> 6;
  int quad = lane >> 4, l15 = lane & 15;
  int bx = blockIdx.x;                       // k-chunk [0,2)
  long m0 = (long)blockIdx.y * 64 + wave * 16;
  long row = m0 + l15;
  int k0 = bx * 512;
  float inv = 1.0f / load_scale(slot);

  const float* xp = x + row * 1024 + k0 + quad * 8;
  const f16* ap = Ah + l15 * 1024 + k0 + quad * 8;
  i8* op = xq + row * 1024 + k0 + quad * 8;
  f32x4 acc = {0.0f, 0.0f, 0.0f, 0.0f};
#pragma unroll
  for (int s = 0; s < 16; s++) {
    float4 v0 = ((const float4*)(xp + s * 32))[0];
    float4 v1 = ((const float4*)(xp + s * 32))[1];
    f16x8 af = {(f16)v0.x, (f16)v0.y, (f16)v0.z, (f16)v0.w,
                (f16)v1.x, (f16)v1.y, (f16)v1.z, (f16)v1.w};
    f16x8 bf = *(const f16x8*)(ap + s * 32);
    acc = __builtin_amdgcn_mfma_f32_16x16x32_f16(af, bf, acc, 0, 0, 0);
    uint2 o = {pack4(v0, inv), pack4(v1, inv)};
    *(uint2*)(op + s * 32) = o;
  }
  if (l15 < 8) {
#pragma unroll
    for (int r = 0; r < 4; r++) {
      long m = m0 + quad * 4 + r;
      atomicAdd(&t1[m * 8 + l15], acc[r]);
    }
  }
}

// ---- fused: quantize h (fp16 -> i8 in place, chunked) + t2 = h.A^T via MFMA
__launch_bounds__(256) __global__
    void quant_h_t2_fused(u16* __restrict__ h,        // [8192][4096] fp16
                          const f16* __restrict__ Ah, // [16][4096]
                          const u32* __restrict__ slot,
                          float* __restrict__ t2) {   // [8192][8], pre-zeroed
  int tid = threadIdx.x;
  int lane = tid & 63, wave = tid >> 6;
  int quad = lane >> 4, l15 = lane & 15;
  int bx = blockIdx.x;                       // k-chunk index [0,8)
  long m0 = (long)blockIdx.y * 64 + wave * 16;
  long row = m0 + l15;
  int k0 = bx * 512;
  float inv = 1.0f / load_scale(slot);

  const u16* hp = h + row * 4096 + k0 + quad * 8;
  const f16* ap = Ah + l15 * 4096 + k0 + quad * 8;
  f32x4 acc = {0.0f, 0.0f, 0.0f, 0.0f};
  u32 q[32];
#pragma unroll
  for (int s = 0; s < 16; s++) {
    uint4 hv = *(const uint4*)(hp + s * 32);   // 8 fp16 of h
    f16x8 af = *(const f16x8*)&hv;
    f16x8 bf = *(const f16x8*)(ap + s * 32);
    acc = __builtin_amdgcn_mfma_f32_16x16x32_f16(af, bf, acc, 0, 0, 0);
    u32 uu[4] = {hv.x, hv.y, hv.z, hv.w};
#pragma unroll
    for (int c = 0; c < 2; c++) {
      float2 f0 = __half22float2(*(__half2*)&uu[2 * c]);
      float2 f1 = __half22float2(*(__half2*)&uu[2 * c + 1]);
      q[2 * s + c] = ((u32)(quanti(f0.x, inv) & 255)) |
                     ((u32)(quanti(f0.y, inv) & 255) << 8) |
                     ((u32)(quanti(f1.x, inv) & 255) << 16) |
                     ((u32)(quanti(f1.y, inv) & 255) << 24);
    }
  }
  asm volatile("" ::: "memory");
  i8* op = (i8*)h + row * 8192 + bx * 1024 + quad * 8;
#pragma unroll
  for (int s = 0; s < 16; s++) {
    uint2 o = {q[2 * s], q[2 * s + 1]};
    *(uint2*)(op + s * 32) = o;
  }
  if (l15 < 8) {
#pragma unroll
    for (int r = 0; r < 4; r++) {
      long m = m0 + quad * 4 + r;
      atomicAdd(&t2[m * 8 + l15], acc[r]);
    }
  }
}

// ---------- pipelined i8 GEMM: C = Aq * Bq^T, BM=BN=128, BK=128 -------------
// 256 threads, 4 waves (2Mx2N), LDS 64KB dbuf -> 2 independent blocks/CU.
// LDS XOR-swizzle: phys 16B-chunk p at row r holds logical chunk p^(r&7)
// (pre-swizzled global source, linear global_load_lds dest).
// Per K-tile t (buf b=t&1), 2 phases:
//   ph1: ds_read a0,a1 (ALL A) + b0; stage B(t+1)->buf b'  | MFMA(a0,b0) x16
//   ph2: ds_read b1;               stage A(t+2)->buf b     | MFMA(a1,b1) x16
//        + vmcnt(4) [A(t+2)'s 4 stay in flight] + barrier.
// Safety: A region of buf b fully read after ph1 (LGKM0 + trailing SBAR on
// every wave) -> ph2's stageA(t+2) into buf b is barrier-separated. B(t+1)
// targets buf b', whose reads finished in tile t-1. vmcnt(4) at tile end
// forces A(t+1)+B(t+1) landed (issue order: A(t+1)[t-1.ph2], B(t+1)[t.ph1],
// A(t+2)[t.ph2]); tail tiles use vmcnt(0).
// MODE 0: *scale+bias+2*t.Bl, GELU, fp16 h store, absmax(h).
// MODE 1: fp32 store; A in CHUNKED col layout (byte (c>>9)*1024+(c&511),
//         rowstride 8192) -> kb = (t>>2)*1024+(t&3)*128.
template <int MODE>
__launch_bounds__(256, 2) __global__
    void gemm4w_kernel(const i8* __restrict__ A, const i8* __restrict__ B,
                       int N, int K, int lda, int ldb,
                       const float* __restrict__ bias,
                       const float* __restrict__ tl,   // [M][8] f32
                       const float* __restrict__ Bl,   // [N][8] f32
                       const u32* __restrict__ scales, int sa, int sb,
                       void* __restrict__ outp, u32* __restrict__ hmax) {
  constexpr int MT = 4, NT = 4;
  __shared__ __align__(16) i8 As[2][128 * 128];
  __shared__ __align__(16) i8 Bs[2][128 * 128];
  __shared__ u32 bmax;
  int tid = threadIdx.x;
  int lane = tid & 63, wave = tid >> 6;
  int quad = lane >> 4, l15 = lane & 15;
  int wm = (wave & 1) * 64, wn = (wave >> 1) * 64;
  // XCD-bijective swizzle (nwg % 8 == 0 for both grids)
  int nwg = gridDim.x * gridDim.y;
  int lin = blockIdx.y * gridDim.x + blockIdx.x;
  int swb = (lin & 7) * (nwg >> 3) + (lin >> 3);
  int bx = swb % gridDim.x, by = swb / gridDim.x;
  long m0 = (long)by * 128;
  long n0 = (long)bx * 128;
  if (MODE == 0 && tid == 0) bmax = 0u;

  // staging: per operand-half (64 rows x 128B = 512 chunks of 16B) each
  // thread loads 2 chunks: c = u*256+tid, row = c>>3, pre-swizzled k-chunk.
  const i8* pA[2];
  const i8* pB[2];
  int ldsOff[2];
#pragma unroll
  for (int u = 0; u < 2; u++) {
    int c = u * 256 + tid;
    int row = c >> 3;
    int swz = ((c & 7) ^ (row & 7)) * 16;
    pA[u] = A + (m0 + row) * lda + swz;
    pB[u] = B + (n0 + row) * ldb + swz;
    ldsOff[u] = c * 16;
  }

  auto stageA = [&](int t, int h) {
    int kb = (MODE == 1) ? ((t >> 2) * 1024 + (t & 3) * 128) : (t << 7);
#pragma unroll
    for (int u = 0; u < 2; u++)
      ASYNC16(pA[u] + (long)h * 64 * lda + kb,
              &As[t & 1][h * 8192 + ldsOff[u]]);
  };
  auto stageB = [&](int t, int h) {
    int kb = t << 7;
#pragma unroll
    for (int u = 0; u < 2; u++)
      ASYNC16(pB[u] + (long)h * 64 * ldb + kb,
              &Bs[t & 1][h * 8192 + ldsOff[u]]);
  };

  // fragment-read swizzled chunk byte offsets: chunk = (kk*4+quad)^(l15&7)
  int s0 = (quad ^ (l15 & 7)) * 16;
  int s1 = s0 ^ 64;

  i32x4 acc[MT][NT] = {};
  int NTILES = K >> 7;

  // prologue: tile0 fully + tile1 A; wait tile0 (A(1)'s 4 may fly)
  stageA(0, 0); stageA(0, 1); stageB(0, 0); stageB(0, 1);
  stageA(1, 0); stageA(1, 1);
  VMCNT(4);
  SBAR;

  for (int t = 0; t < NTILES; t++) {
    const i8* Ab = As[t & 1];
    const i8* Bb = Bs[t & 1];
    i32x4 a0[MT], a1[MT], b0[NT], b1[NT];
    // ---- phase 1: read ALL A (a0,a1) + b0; stage B(t+1); MFMA(a0,b0)
#pragma unroll
    for (int i = 0; i < MT; i++) {
      a0[i] = *(const i32x4*)(Ab + (wm + i * 16 + l15) * 128 + s0);
      a1[i] = *(const i32x4*)(Ab + (wm + i * 16 + l15) * 128 + s1);
    }
#pragma unroll
    for (int j = 0; j < NT; j++)
      b0[j] = *(const i32x4*)(Bb + (wn + j * 16 + l15) * 128 + s0);
    if (t + 1 < NTILES) { stageB(t + 1, 0); stageB(t + 1, 1); }
    SBAR;
    LGKM0;
    __builtin_amdgcn_s_setprio(1);
#pragma unroll
    for (int i = 0; i < MT; i++)
#pragma unroll
      for (int j = 0; j < NT; j++)
        acc[i][j] = __builtin_amdgcn_mfma_i32_16x16x64_i8(a0[i], b0[j],
                                                          acc[i][j], 0, 0, 0);
    __builtin_amdgcn_s_setprio(0);
    SBAR;
    // ---- phase 2: read b1; stage A(t+2) into consumed buf; MFMA(a1,b1)
#pragma unroll
    for (int j = 0; j < NT; j++)
      b1[j] = *(const i32x4*)(Bb + (wn + j * 16 + l15) * 128 + s1);
    if (t + 2 < NTILES) { stageA(t + 2, 0); stageA(t + 2, 1); }
    SBAR;
    LGKM0;
    __builtin_amdgcn_s_setprio(1);
#pragma unroll
    for (int i = 0; i < MT; i++)
#pragma unroll
      for (int j = 0; j < NT; j++)
        acc[i][j] = __builtin_amdgcn_mfma_i32_16x16x64_i8(a1[i], b1[j],
                                                          acc[i][j], 0, 0, 0);
    __builtin_amdgcn_s_setprio(0);
    if (t + 2 < NTILES) {
      VMCNT(4);   // A(t+2)'s 4 loads stay in flight; A(t+1)+B(t+1) landed
    } else {
      VMCNT(0);   // tail
    }
    SBAR;
  }

  // epilogue
  float scale = load_scale(scales + sa) * load_scale(scales + sb);
  float biasv[NT];
  float4 bl0[NT], bl1[NT];
#pragma unroll
  for (int j = 0; j < NT; j++) {
    long n = n0 + wn + j * 16 + l15;
    biasv[j] = bias[n];
    bl0[j] = ((const float4*)(Bl + n * 8))[0];
    bl1[j] = ((const float4*)(Bl + n * 8))[1];
  }
  float lmax = 0.0f;
#pragma unroll
  for (int i = 0; i < MT; i++) {
#pragma unroll
    for (int r = 0; r < 4; r++) {
      long m = m0 + wm + i * 16 + quad * 4 + r;
      float4 t0 = ((const float4*)(tl + m * 8))[0];
      float4 t1v = ((const float4*)(tl + m * 8))[1];
#pragma unroll
      for (int j = 0; j < NT; j++) {
        long n = n0 + wn + j * 16 + l15;
        float lora = t0.x * bl0[j].x + t0.y * bl0[j].y + t0.z * bl0[j].z +
                     t0.w * bl0[j].w + t1v.x * bl1[j].x + t1v.y * bl1[j].y +
                     t1v.z * bl1[j].z + t1v.w * bl1[j].w;
        float v = (float)acc[i][j][r] * scale + biasv[j] + 2.0f * lora;
        if (MODE == 0) {
          float hv = gelu_erf(v);
          __half hh = __float2half_rn(hv);
          ((u16*)outp)[m * N + n] = *(u16*)&hh;
          lmax = fmaxf(lmax, fabsf(hv));
        } else {
          ((float*)outp)[m * N + n] = v;
        }
      }
    }
  }
  if (MODE == 0) {
    atomicMax(&bmax, __float_as_uint(lmax));
    __syncthreads();
    if (tid == 0) atomicMax(hmax, bmax);
  }
}

extern "C" void kernel_launch(void* const* d_in, const int* in_sizes, int n_in,
                              void* d_out, int out_size, void* d_ws,
                              size_t ws_size, hipStream_t stream) {
  const float* x = (const float*)d_in[0];    // [8192][1024]
  const float* Wfc = (const float*)d_in[1];  // [4096][1024]
  const float* bfc = (const float*)d_in[2];  // [4096]
  const float* Afc = (const float*)d_in[3];  // [8][1024]
  const float* Bfc = (const float*)d_in[4];  // [4096][8]
  const float* Wpr = (const float*)d_in[5];  // [1024][4096]
  const float* bpr = (const float*)d_in[6];  // [1024]
  const float* Apr = (const float*)d_in[7];  // [8][4096]
  const float* Bpr = (const float*)d_in[8];  // [1024][8]
  float* out = (float*)d_out;                // fp32 [8192][1024]

  char* w = (char*)d_ws;
  u32* scales = (u32*)w;                   // 4 slots (fp32 bits): x, Wfc, Wpr, h
  float* t1 = (float*)(w + 256);           // [8192][8]
  float* t2 = (float*)(w + 256 + 262144);  // [8192][8]
  i8* xq = (i8*)(w + 524544);              // [8192][1024] i8
  f16* aprh = (f16*)(w + 8913152);         // [16][4096] fp16
  f16* afch = (f16*)(w + 9175040);         // [16][1024] fp16 (gap before wq1)
  i8* wq1 = (i8*)(w + 9437184);            // [4096][1024] i8
  i8* wq2 = (i8*)(w + 13631488);           // [1024][4096] i8
  u16* hq = (u16*)(w + 17825792);          // [8192][4096] fp16 h; i8 in place
  if (ws_size < 84934656) return;          // need ~81 MiB scratch

  hipMemsetAsync(w, 0, 524544, stream);    // scales + t1 + t2 (atomicAdd'd)
  conv_a16_kernel<<<32, 256, 0, stream>>>(Apr, aprh, 4096);
  conv_a16_kernel<<<8, 256, 0, stream>>>(Afc, afch, 1024);
  absmax_kernel<<<1024, 256, 0, stream>>>(x, 8192 * 1024 / 4, scales + 0);
  absmax_kernel<<<512, 256, 0, stream>>>(Wfc, 4096 * 1024 / 4, scales + 1);
  absmax_kernel<<<512, 256, 0, stream>>>(Wpr, 4096 * 1024 / 4, scales + 2);
  quant_x_t1_fused<<<dim3(2, 128), 256, 0, stream>>>(x, afch, scales + 0, xq,
                                                     t1);
  quant_w_kernel<<<256, 256, 0, stream>>>(Wfc, 4096 * 1024 / 16, scales + 1,
                                          wq1);
  quant_w_kernel<<<256, 256, 0, stream>>>(Wpr, 4096 * 1024 / 16, scales + 2,
                                          wq2);
  // gemm1: 8192x4096, K=1024, grid (32,64)=2048 (%8==0)
  gemm4w_kernel<0><<<dim3(32, 64), 256, 0, stream>>>(
      xq, wq1, 4096, 1024, 1024, 1024, bfc, t1, Bfc, scales, 0, 1, hq,
      scales + 3);
  quant_h_t2_fused<<<dim3(8, 128), 256, 0, stream>>>(hq, aprh, scales + 3, t2);
  // gemm2: 8192x1024, K=4096, grid (8,64)=512 (%8==0) — all resident
  gemm4w_kernel<1><<<dim3(8, 64), 256, 0, stream>>>(
      (const i8*)hq, wq2, 1024, 4096, 8192, 4096, bpr, t2, Bpr, scales, 3, 2,
      out, nullptr);
}